// Round 12
// baseline (86.642 us; speedup 1.0000x reference)
//
#include <hip/hip_runtime.h>
#include <hip/hip_fp16.h>
#include <math.h>

#define A_N   180
#define HR_N  512
#define H_OUT 512
#define W_OUT 512
#define HP    614              // H_OUT + 2*51
#define WP    614
#define NPIX  (H_OUT * W_OUT)

#define TILE  16               // 16x16 pixel tile, 1024 blocks (exactly 4/CU)
#define QA    45               // angles per wave (4 waves = 4 quarters)
#define WIN   24               // window entries per angle

// Single fused kernel: no workspace, no prep dispatch.
// Each block: trig + window bases -> stage fp16 windows straight from sino -> accumulate.

__device__ __forceinline__ __half2 samp2(const float* __restrict__ sino, int a, int yy) {
    // {b0(yy), b1(yy)} of the detector-axis resample; 0 outside [0, HP)
    if (yy < 0 || yy >= HP) return __float2half2_rn(0.0f);
    float src = ((float)yy + 0.5f) * ((float)HR_N / (float)HP) - 0.5f;
    src = fminf(fmaxf(src, 0.0f), (float)(HR_N - 1));
    int i0 = (int)floorf(src);
    int i1 = min(i0 + 1, HR_N - 1);
    float w = src - (float)i0;
    const float* r0 = sino + (size_t)a * HR_N;           // batch 0
    const float* r1 = sino + (size_t)(A_N + a) * HR_N;   // batch 1
    float b0 = fmaf(w, r0[i1] - r0[i0], r0[i0]);
    float b1 = fmaf(w, r1[i1] - r1[i0], r1[i0]);
    return __floats2half2_rn(b0, b1);
}

__global__ __launch_bounds__(256, 4) void bp_kernel(const float* __restrict__ sino,
                                                    const float* __restrict__ angles,
                                                    float* __restrict__ out) {
    __shared__ float2 s_tg[A_N];           // 1.44 KB
    __shared__ int    s_base[A_N];         // 0.72 KB
    __shared__ uint2  s_win[A_N * WIN];    // 34.56 KB -> 36.72 KB total (4 blocks/CU)

    int t  = threadIdx.x;
    int tx = blockIdx.x, ty = blockIdx.y;
    float Xc = (float)(tx * TILE) - 248.0f;   // tile center (= +7.5 - 255.5)
    float Yc = (float)(ty * TILE) - 248.0f;

    if (t < A_N) {
        float th = -angles[t] * (float)(M_PI / 180.0);
        float c = cosf(th), s = sinf(th);
        s_tg[t] = make_float2(c, s);
        float iyc = fmaf(s, Xc, fmaf(c, Yc, 306.5f));
        s_base[t] = (int)floorf(iyc) - 11;    // window covers [base, base+23]
    }
    __syncthreads();

    // Stage ALL 180 angle-windows directly from sino (fp16-packed, zero OOB)
    for (int e = t; e < A_N * WIN; e += 256) {
        int wid = e / WIN;
        int j   = e - wid * WIN;
        int yy  = s_base[wid] + j;            // image coords, may be OOB -> 0
        __half2 lo = samp2(sino, wid, yy);
        __half2 hi = samp2(sino, wid, yy + 1);
        uint2 u;
        u.x = *(unsigned int*)&lo;
        u.y = *(unsigned int*)&hi;
        s_win[e] = u;
    }
    __syncthreads();

    // Wave q handles angles [q*45, q*45+45); lane -> 4 adjacent x pixels
    int q    = t >> 6;
    int lane = t & 63;
    int xq   = lane & 3;
    int yy   = lane >> 2;
    int x0   = tx * TILE + xq * 4;
    int y0   = ty * TILE + yy;
    float X  = (float)x0 - 255.5f;
    float Y  = (float)y0 - 255.5f;

    float2 acc[4] = {{0,0},{0,0},{0,0},{0,0}};   // [g] = {batch0, batch1}

    bool interior = (Xc * Xc + Yc * Yc) <= 87500.0f;  // ix in [0,613] always
    const int abase = q * QA;
    const uint2* winq = s_win + abase * WIN;

    if (interior) {
        __half2 hacc[4] = {__float2half2_rn(0.0f), __float2half2_rn(0.0f),
                           __float2half2_rn(0.0f), __float2half2_rn(0.0f)};
#pragma unroll 5
        for (int la = 0; la < QA; ++la) {
            float2 cs = s_tg[abase + la];         // broadcast ds_read_b64
            float c = cs.x, s = cs.y;
            float iyc = fmaf(s, Xc, fmaf(c, Yc, 306.5f));
            float Kf  = 317.5f - floorf(iyc);     // exact: 306.5 - base
            float fg  = fmaf(s, X, fmaf(c, Y, Kf));   // in (0.39, 22.61)
#pragma unroll
            for (int g = 0; g < 4; ++g) {
                int   li = (int)fg;
                float wy = fg - (float)li;
                uint2 cv = winq[la * WIN + li];   // ds_read_b64
                __half2 lo = *(__half2*)&cv.x;
                __half2 hi = *(__half2*)&cv.y;
                hacc[g] = __hadd2(hacc[g],
                                  __hfma2(__float2half2_rn(wy), __hsub2(hi, lo), lo));
                fg += s;
            }
        }
#pragma unroll
        for (int g = 0; g < 4; ++g) {
            acc[g].x = __low2float(hacc[g]);
            acc[g].y = __high2float(hacc[g]);
        }
    } else {
#pragma unroll 5
        for (int la = 0; la < QA; ++la) {
            float2 cs = s_tg[abase + la];
            float c = cs.x, s = cs.y;
            float iyc = fmaf(s, Xc, fmaf(c, Yc, 306.5f));
            float Kf  = 317.5f - floorf(iyc);
            float fg  = fmaf(s, X, fmaf(c, Y, Kf));
            float ixg = fmaf(c, X, fmaf(-s, Y, 306.5f));
#pragma unroll
            for (int g = 0; g < 4; ++g) {
                int   li = (int)fg;
                float wy = fg - (float)li;
                uint2 cv = winq[la * WIN + li];
                __half2 lo = *(__half2*)&cv.x;
                __half2 hi = *(__half2*)&cv.y;
                __half2 r2 = __hfma2(__float2half2_rn(wy), __hsub2(hi, lo), lo);
                float xf = fminf(fmaxf(ixg + 1.0f, 0.0f), 1.0f)
                         * fminf(fmaxf((float)WP - ixg, 0.0f), 1.0f);
                acc[g].x = fmaf(xf, __low2float(r2),  acc[g].x);
                acc[g].y = fmaf(xf, __high2float(r2), acc[g].y);
                fg += s; ixg += c;
            }
        }
    }

    // Quarter reduction: reuse the window LDS (safe after barrier)
    __syncthreads();
    float* red = (float*)s_win;               // 3 quarters * 2 batches * 256 px = 6 KB
    int px = yy * TILE + xq * 4;
    if (q != 0) {
        int o = (q - 1) * 512;
#pragma unroll
        for (int g = 0; g < 4; ++g) {
            red[o + px + g]       = acc[g].x;
            red[o + 256 + px + g] = acc[g].y;
        }
    }
    __syncthreads();
    if (q == 0) {
        const float inv = 1.0f / (180.0f + 1e-6f);
        float4 r0, r1;
        float* p0 = &r0.x; float* p1 = &r1.x;
#pragma unroll
        for (int g = 0; g < 4; ++g) {
            p0[g] = (acc[g].x + red[px + g]       + red[512 + px + g]       + red[1024 + px + g])       * inv;
            p1[g] = (acc[g].y + red[256 + px + g] + red[512 + 256 + px + g] + red[1024 + 256 + px + g]) * inv;
        }
        int idx = y0 * W_OUT + x0;
        *(float4*)&out[idx]        = r0;
        *(float4*)&out[NPIX + idx] = r1;
    }
}

extern "C" void kernel_launch(void* const* d_in, const int* in_sizes, int n_in,
                              void* d_out, int out_size, void* d_ws, size_t ws_size,
                              hipStream_t stream) {
    const float* sino   = (const float*)d_in[0];
    const float* angles = (const float*)d_in[1];
    (void)d_ws; (void)ws_size;

    dim3 grid(W_OUT / TILE, H_OUT / TILE);    // 32 x 32 = 1024 blocks
    bp_kernel<<<grid, 256, 0, stream>>>(sino, angles, (float*)d_out);
}

// Round 13
// 84.566 us; speedup vs baseline: 1.0245x; 1.0245x over previous
//
#include <hip/hip_runtime.h>
#include <hip/hip_fp16.h>
#include <math.h>

#define B_N   2
#define A_N   180
#define HR_N  512
#define H_OUT 512
#define W_OUT 512
#define HP    614              // H_OUT + 2*51
#define WP    614
#define GUARD 80               // zero guard each side
#define HPP   (HP + 2*GUARD)   // 774
#define NPIX  (H_OUT * W_OUT)

#define TILE  16               // 16x16 pixel tile, 1024 blocks (exactly 4/CU)
#define QA    45               // angles per wave (4 waves = 4 quarters)
#define WIN   24               // window entries per angle (f in (0.39, 22.61))

// Workspace:
//   pk2[A_N][HPP] uint2: {lo = half2(b0[y],b1[y]), d = half2(b0,b1)[y+1] - lo}
//   tg[A_N] float2: {cos, sin}

__device__ __forceinline__ float rdlane(float v, int la) {
    return __uint_as_float(__builtin_amdgcn_readlane(__float_as_uint(v), la));
}

__device__ __forceinline__ float col_val(const float* __restrict__ sino,
                                         int b, int a, int yy) {
    if (yy < 0 || yy >= HP) return 0.0f;
    float src = ((float)yy + 0.5f) * ((float)HR_N / (float)HP) - 0.5f;
    src = fminf(fmaxf(src, 0.0f), (float)(HR_N - 1));
    int i0 = (int)floorf(src);
    int i1 = min(i0 + 1, HR_N - 1);
    float wH = src - (float)i0;
    const float* srow = sino + ((size_t)b * A_N + a) * HR_N;
    return srow[i0] * (1.0f - wH) + srow[i1] * wH;
}

__global__ void prep_kernel(const float* __restrict__ sino,
                            const float* __restrict__ angles,
                            uint2* __restrict__ pk2,
                            float2* __restrict__ tg) {
    int idx = blockIdx.x * blockDim.x + threadIdx.x;
    if (idx < A_N) {
        float th = -angles[idx] * (float)(M_PI / 180.0);
        tg[idx] = make_float2(cosf(th), sinf(th));
    }
    const int total = A_N * HPP;
    if (idx < total) {
        int y = idx % HPP;
        int a = idx / HPP;
        int yy = y - GUARD;
        __half2 lo = __floats2half2_rn(col_val(sino, 0, a, yy),
                                       col_val(sino, 1, a, yy));
        __half2 hi = __floats2half2_rn(col_val(sino, 0, a, yy + 1),
                                       col_val(sino, 1, a, yy + 1));
        __half2 d  = __hsub2(hi, lo);
        uint2 u;
        u.x = *(unsigned int*)&lo;
        u.y = *(unsigned int*)&d;
        pk2[idx] = u;
    }
}

__global__ __launch_bounds__(256, 4) void bp_kernel(const uint2* __restrict__ pk2,
                                                    const float2* __restrict__ tgv,
                                                    float* __restrict__ out) {
    __shared__ float2 s_tg[A_N];           // 1.44 KB
    __shared__ int    s_base[A_N];         // 0.72 KB
    __shared__ uint2  s_win[A_N * WIN];    // 34.56 KB -> 36.72 KB total (4 blocks/CU)

    int t  = threadIdx.x;
    int tx = blockIdx.x, ty = blockIdx.y;
    float Xc = (float)(tx * TILE) - 248.0f;   // tile center (= +7.5 - 255.5)
    float Yc = (float)(ty * TILE) - 248.0f;

    if (t < A_N) {
        float2 cs = tgv[t];
        s_tg[t] = cs;
        float iyc = fmaf(cs.y, Xc, fmaf(cs.x, Yc, 306.5f));
        s_base[t] = (int)floorf(iyc) - 11;    // window covers [base, base+23]
    }
    __syncthreads();

    // Stage ALL 180 angle-windows once (4320 uint2, ~17 loads/thread)
    for (int e = t; e < A_N * WIN; e += 256) {
        int wid = e / WIN;
        int j   = e - wid * WIN;
        s_win[e] = pk2[(size_t)wid * HPP + (GUARD + s_base[wid] + j)];
    }

    // Wave q handles angles [q*QA, q*QA+QA); lane -> 4 adjacent x pixels.
    // Lanes 0..44 pre-load their angle's constants; loop reads them via
    // v_readlane (VALU pipe) so the inner loop issues ZERO trig LDS reads.
    int q    = t >> 6;
    int lane = t & 63;
    int la0  = lane < QA ? lane : QA - 1;
    float vC, vS, vK;
    {
        float2 cs = s_tg[q * QA + la0];
        float iyc = fmaf(cs.y, Xc, fmaf(cs.x, Yc, 306.5f));
        vC = cs.x; vS = cs.y;
        vK = 317.5f - floorf(iyc);            // exact: 306.5 - base + 11
    }

    int xq = lane & 3;
    int yy = lane >> 2;
    int x0 = tx * TILE + xq * 4;
    int y0 = ty * TILE + yy;
    float X = (float)x0 - 255.5f;
    float Y = (float)y0 - 255.5f;

    __syncthreads();

    float2 acc[4] = {{0,0},{0,0},{0,0},{0,0}};   // [g] = {batch0, batch1}
    bool interior = (Xc * Xc + Yc * Yc) <= 87500.0f;  // ix in [0,613] always
    const uint2* winq = s_win + q * QA * WIN;

    if (interior) {
        __half2 hacc[4] = {__float2half2_rn(0.0f), __float2half2_rn(0.0f),
                           __float2half2_rn(0.0f), __float2half2_rn(0.0f)};
        for (int la = 0; la < QA; ++la) {
            float c = rdlane(vC, la), s = rdlane(vS, la), K = rdlane(vK, la);
            float fg = fmaf(s, X, fmaf(c, Y, K));     // in (0.39, 22.61)
#pragma unroll
            for (int g = 0; g < 4; ++g) {
                int   li = (int)fg;
                float wy = fg - (float)li;
                uint2 cv = winq[la * WIN + li];       // ds_read_b64 (the only LDS op)
                __half2 lo = *(__half2*)&cv.x;
                __half2 d  = *(__half2*)&cv.y;
                hacc[g] = __hadd2(hacc[g], __hfma2(__float2half2_rn(wy), d, lo));
                fg += s;
            }
        }
#pragma unroll
        for (int g = 0; g < 4; ++g) {
            acc[g].x = __low2float(hacc[g]);
            acc[g].y = __high2float(hacc[g]);
        }
    } else {
        for (int la = 0; la < QA; ++la) {
            float c = rdlane(vC, la), s = rdlane(vS, la), K = rdlane(vK, la);
            float fg  = fmaf(s, X, fmaf(c, Y, K));
            float ixg = fmaf(c, X, fmaf(-s, Y, 306.5f));
#pragma unroll
            for (int g = 0; g < 4; ++g) {
                int   li = (int)fg;
                float wy = fg - (float)li;
                uint2 cv = winq[la * WIN + li];
                __half2 lo = *(__half2*)&cv.x;
                __half2 d  = *(__half2*)&cv.y;
                __half2 r2 = __hfma2(__float2half2_rn(wy), d, lo);
                float xf = fminf(fmaxf(ixg + 1.0f, 0.0f), 1.0f)
                         * fminf(fmaxf((float)WP - ixg, 0.0f), 1.0f);
                acc[g].x = fmaf(xf, __low2float(r2),  acc[g].x);
                acc[g].y = fmaf(xf, __high2float(r2), acc[g].y);
                fg += s; ixg += c;
            }
        }
    }

    // Quarter reduction: reuse the window LDS (safe after barrier)
    __syncthreads();
    float* red = (float*)s_win;               // 3 quarters * 2 batches * 256 px = 6 KB
    int px = yy * TILE + xq * 4;
    if (q != 0) {
        int o = (q - 1) * 512;
#pragma unroll
        for (int g = 0; g < 4; ++g) {
            red[o + px + g]       = acc[g].x;
            red[o + 256 + px + g] = acc[g].y;
        }
    }
    __syncthreads();
    if (q == 0) {
        const float inv = 1.0f / (180.0f + 1e-6f);
        float4 r0, r1;
        float* p0 = &r0.x; float* p1 = &r1.x;
#pragma unroll
        for (int g = 0; g < 4; ++g) {
            p0[g] = (acc[g].x + red[px + g]       + red[512 + px + g]       + red[1024 + px + g])       * inv;
            p1[g] = (acc[g].y + red[256 + px + g] + red[512 + 256 + px + g] + red[1024 + 256 + px + g]) * inv;
        }
        int idx = y0 * W_OUT + x0;
        *(float4*)&out[idx]        = r0;
        *(float4*)&out[NPIX + idx] = r1;
    }
}

extern "C" void kernel_launch(void* const* d_in, const int* in_sizes, int n_in,
                              void* d_out, int out_size, void* d_ws, size_t ws_size,
                              hipStream_t stream) {
    const float* sino   = (const float*)d_in[0];
    const float* angles = (const float*)d_in[1];
    char*   ws  = (char*)d_ws;
    uint2*  pk2 = (uint2*)ws;                              // A_N * HPP * 8 B
    float2* tg  = (float2*)(ws + (size_t)A_N * HPP * sizeof(uint2));

    const int total = A_N * HPP;
    prep_kernel<<<(total + 255) / 256, 256, 0, stream>>>(sino, angles, pk2, tg);

    dim3 grid(W_OUT / TILE, H_OUT / TILE);                 // 32 x 32 = 1024 blocks
    bp_kernel<<<grid, 256, 0, stream>>>(pk2, tg, (float*)d_out);
}